// Round 13
// baseline (1383.378 us; speedup 1.0000x reference)
//
#include <hip/hip_runtime.h>
#include <hip/hip_bf16.h>

#define NPTS    4096
#define NBATCH  16
#define NPOINT  1024
#define NSAMPLE 32

typedef float v2f __attribute__((ext_vector_type(2)));
typedef unsigned long long ull;

// ---------------- DPP helpers (wave reductions without LDS round-trips) ---
#define ROW_SHR1  0x111
#define ROW_SHR2  0x112
#define ROW_SHR4  0x114
#define ROW_SHR8  0x118
#define ROW_BC15  0x142
#define ROW_BC31  0x143

template<int CTRL>
__device__ __forceinline__ unsigned dpp_mov(unsigned v) {
    // bound_ctrl=true: invalid source lanes produce 0 (safe identity: vals >= 0)
    return (unsigned)__builtin_amdgcn_update_dpp(0, (int)v, CTRL, 0xF, 0xF, true);
}
template<int CTRL>
__device__ __forceinline__ float dpp_maxf(float v) {
    unsigned t = dpp_mov<CTRL>(__float_as_uint(v));
    return fmaxf(v, __uint_as_float(t));
}

// ---------------- control block in workspace ---------------------------------
// ctrl[0..15]  : per-batch FPS progress (last completed iteration, rel/acq)
// ctrl[16]     : U+setup completion counter (240 consumer blocks)
// ctrl[17]     : work-item queue head
#define CTRL_DONE  16
#define CTRL_QHEAD 17
#define NCONS      240
#define NITEMS     2048          // 16384 centroids / 8 per item

// ---------------- U precompute ----------------------------------------------
// U[b*4096+p][o] = sum_{c<64} w0[o][3+c] * points[b][c][p]
__device__ void u_role(int g, const float* __restrict__ points,
                       const float* __restrict__ w0, float* __restrict__ U)
{
    const int b = g >> 12, p = g & (NPTS - 1);
    const float* pb = points + (size_t)b * 64 * NPTS + p;
    float in[64];
    #pragma unroll
    for (int c = 0; c < 64; ++c) in[c] = pb[c * NPTS];

    float* ug = U + (size_t)g * 64;
    for (int o4 = 0; o4 < 64; o4 += 4) {
        const float* r0 = w0 + (o4+0)*67 + 3;
        const float* r1 = w0 + (o4+1)*67 + 3;
        const float* r2 = w0 + (o4+2)*67 + 3;
        const float* r3 = w0 + (o4+3)*67 + 3;
        float a0 = 0.f, a1 = 0.f, a2 = 0.f, a3 = 0.f;
        #pragma unroll
        for (int c = 0; c < 64; ++c) {
            const float x = in[c];
            a0 = fmaf(r0[c], x, a0);
            a1 = fmaf(r1[c], x, a1);
            a2 = fmaf(r2[c], x, a2);
            a3 = fmaf(r3[c], x, a3);
        }
        *(float4*)(ug + o4) = make_float4(a0, a1, a2, a3);
    }
}

// ---------------- setup: transpose + BN fold ---------------------------------
__device__ void setup_role(
    const float* __restrict__ w0, const float* __restrict__ b0,
    const float* __restrict__ g0, const float* __restrict__ be0,
    const float* __restrict__ m0, const float* __restrict__ v0,
    const float* __restrict__ w1, const float* __restrict__ b1,
    const float* __restrict__ g1, const float* __restrict__ be1,
    const float* __restrict__ m1, const float* __restrict__ v1,
    const float* __restrict__ b2, const float* __restrict__ g2,
    const float* __restrict__ be2, const float* __restrict__ m2,
    const float* __restrict__ v2, float* __restrict__ wp)
{
    const int t = threadIdx.x;
    for (int i = t; i < 3*64; i += 256) {
        int k = i >> 6, o = i & 63;
        wp[i] = w0[o*67 + k];                      // w0t3 [3][64]
    }
    for (int i = t; i < 64*64; i += 256) {
        int o = i >> 6, k = i & 63;
        wp[192 + k*64 + o] = w1[i];                // w1t [64][64]
    }
    if (t < 64) {
        float s0 = g0[t] / sqrtf(v0[t] + 1e-5f);
        wp[4288 + t] = s0;
        wp[4352 + t] = (b0[t] - m0[t]) * s0 + be0[t];
        float s1 = g1[t] / sqrtf(v1[t] + 1e-5f);
        wp[4416 + t] = s1;
        wp[4480 + t] = (b1[t] - m1[t]) * s1 + be1[t];
    }
    if (t < 128) {
        float s2 = g2[t] / sqrtf(v2[t] + 1e-5f);
        wp[4544 + t] = s2;
        wp[4672 + t] = (b2[t] - m2[t]) * s2 + be2[t];
    }
}

// ---------------- fused persistent kernel ------------------------------------
// Identical structure to the round-7 kernel that ran and passed (256 blocks,
// all co-resident at 1 block/CU). ONE change: the consumer MLP reads weights
// as wave-uniform SCALAR loads from global wp (scalar pipe, concurrent with
// VALU) instead of per-FMA ds_read from an LDS copy - removes the 1:1
// ds_read:v_fma issue serialization that made consumers ~4x too slow.
__global__ __launch_bounds__(256) void fused_kernel(
    const float* __restrict__ xyz, const float* __restrict__ points,
    const float* __restrict__ w0, const float* __restrict__ b0,
    const float* __restrict__ g0, const float* __restrict__ be0,
    const float* __restrict__ m0w, const float* __restrict__ v0,
    const float* __restrict__ w1, const float* __restrict__ b1,
    const float* __restrict__ g1, const float* __restrict__ be1,
    const float* __restrict__ m1w, const float* __restrict__ v1,
    const float* __restrict__ w2, const float* __restrict__ b2,
    const float* __restrict__ g2, const float* __restrict__ be2,
    const float* __restrict__ m2w, const float* __restrict__ v2,
    float* __restrict__ newxyz, float* __restrict__ out1,
    float* __restrict__ U, float* __restrict__ wp, int* __restrict__ ctrl)
{
    #pragma clang fp contract(off)
    __shared__ __align__(16) char smem[65728];
    __shared__ int item_s;

    if (blockIdx.x < 16) {
        // ================= FPS producer (verified r7 code, unchanged) ========
        __builtin_amdgcn_s_setprio(2);             // win issue arbitration on CU
        float4* P     = reinterpret_cast<float4*>(smem);              // [4096]
        ull*    slotk = reinterpret_cast<ull*>(smem + 65536);         // [2][4]
        float4* slotc = reinterpret_cast<float4*>(smem + 65600);      // [2][4]

        const int b    = blockIdx.x;
        const int tid  = threadIdx.x;
        const int lane = tid & 63;
        const int w    = tid >> 6;
        const float* xb = xyz + (size_t)b * 3 * NPTS;

        v2f px2[8], py2[8], pz2[8], dist2[8];
        #pragma unroll
        for (int q = 0; q < 4; ++q) {
            const int n4 = tid * 16 + q * 4;
            float4 xs = *(const float4*)(xb + n4);
            float4 ys = *(const float4*)(xb + NPTS + n4);
            float4 zs = *(const float4*)(xb + 2*NPTS + n4);
            px2[2*q+0] = (v2f){xs.x, xs.y}; px2[2*q+1] = (v2f){xs.z, xs.w};
            py2[2*q+0] = (v2f){ys.x, ys.y}; py2[2*q+1] = (v2f){ys.z, ys.w};
            pz2[2*q+0] = (v2f){zs.x, zs.y}; pz2[2*q+1] = (v2f){zs.z, zs.w};
            P[n4+0] = make_float4(xs.x, ys.x, zs.x, 0.f);
            P[n4+1] = make_float4(xs.y, ys.y, zs.y, 0.f);
            P[n4+2] = make_float4(xs.z, ys.z, zs.z, 0.f);
            P[n4+3] = make_float4(xs.w, ys.w, zs.w, 0.f);
        }
        #pragma unroll
        for (int j = 0; j < 8; ++j) dist2[j] = (v2f){1e10f, 1e10f};
        __syncthreads();

        float4 c0 = P[0];
        float cx = c0.x, cy = c0.y, cz = c0.z;
        if (tid == 0) {
            newxyz[b*3*NPOINT + 0]        = cx;
            newxyz[b*3*NPOINT + NPOINT]   = cy;
            newxyz[b*3*NPOINT + 2*NPOINT] = cz;
        }

        for (int i = 1; i < NPOINT; ++i) {
            const int s = i & 1;
            const v2f cx2 = (v2f){cx, cx};
            const v2f cy2 = (v2f){cy, cy};
            const v2f cz2 = (v2f){cz, cz};
            float bv = -1.0f; int bj = 0;
            #pragma unroll
            for (int j2 = 0; j2 < 8; ++j2) {
                v2f dx = px2[j2] - cx2;
                v2f dy = py2[j2] - cy2;
                v2f dz = pz2[j2] - cz2;
                v2f xx = dx*dx, yy = dy*dy, zz = dz*dz;
                v2f dd = (xx + yy) + zz;       // same assoc as np: (x2+y2)+z2
                v2f nd;
                nd.x = fminf(dist2[j2].x, dd.x);
                nd.y = fminf(dist2[j2].y, dd.y);
                dist2[j2] = nd;
                if (nd.x > bv) { bv = nd.x; bj = 2*j2; }     // strict >: first max
                if (nd.y > bv) { bv = nd.y; bj = 2*j2+1; }
            }
            const int myidx = (tid << 4) | bj;

            float wv = bv;
            wv = dpp_maxf<ROW_SHR1>(wv);
            wv = dpp_maxf<ROW_SHR2>(wv);
            wv = dpp_maxf<ROW_SHR4>(wv);
            wv = dpp_maxf<ROW_SHR8>(wv);
            wv = dpp_maxf<ROW_BC15>(wv);
            wv = dpp_maxf<ROW_BC31>(wv);                 // lane 63 = wave max
            float wmax = __uint_as_float(
                (unsigned)__builtin_amdgcn_readlane((int)__float_as_uint(wv), 63));
            ull mask = __ballot(bv == wmax);
            int L = (int)__builtin_ctzll(mask);          // first lane = min idx
            int widx = __builtin_amdgcn_readlane(myidx, L);

            float4 cand = P[widx];                       // uniform-addr broadcast
            if (lane == 0) {
                slotk[s*4 + w] = ((ull)__float_as_uint(wmax) << 32) |
                                 (ull)(unsigned)(~widx);
                slotc[s*4 + w] = cand;
            }
            __syncthreads();

            ull k0 = slotk[s*4+0], k1 = slotk[s*4+1];
            ull k2 = slotk[s*4+2], k3 = slotk[s*4+3];
            float4 s0 = slotc[s*4+0], s1 = slotc[s*4+1];
            float4 s2 = slotc[s*4+2], s3 = slotc[s*4+3];
            bool b01 = k1 > k0;
            ull ka = b01 ? k1 : k0;
            float ax = b01 ? s1.x : s0.x, ay = b01 ? s1.y : s0.y, az = b01 ? s1.z : s0.z;
            bool b23 = k3 > k2;
            ull kb = b23 ? k3 : k2;
            float bx = b23 ? s3.x : s2.x, by = b23 ? s3.y : s2.y, bz = b23 ? s3.z : s2.z;
            bool ab = kb > ka;
            cx = ab ? bx : ax; cy = ab ? by : ay; cz = ab ? bz : az;

            if (tid == 0) {
                newxyz[b*3*NPOINT + i]            = cx;
                newxyz[b*3*NPOINT + NPOINT + i]   = cy;
                newxyz[b*3*NPOINT + 2*NPOINT + i] = cz;
                if ((i & 15) == 15)
                    __hip_atomic_store(&ctrl[b], i, __ATOMIC_RELEASE,
                                       __HIP_MEMORY_SCOPE_AGENT);
            }
        }
        return;
    }

    // ================= consumer: U/setup, then streamed ball+mlp =============
    __builtin_amdgcn_s_setprio(0);
    const int cb  = blockIdx.x - 16;               // 0..239
    const int tid = threadIdx.x;

    // phase 0: U slice (+ weight prep on first consumer)
    for (int g = cb * 256 + tid; g < NBATCH * NPTS; g += NCONS * 256)
        u_role(g, points, w0, U);
    if (cb == 0)
        setup_role(w0,b0,g0,be0,m0w,v0, w1,b1,g1,be1,m1w,v1,
                   b2,g2,be2,m2w,v2, wp);
    __syncthreads();
    if (tid == 0) {
        __hip_atomic_fetch_add(&ctrl[CTRL_DONE], 1, __ATOMIC_ACQ_REL,
                               __HIP_MEMORY_SCOPE_AGENT);
        while (__hip_atomic_load(&ctrl[CTRL_DONE], __ATOMIC_ACQUIRE,
                                 __HIP_MEMORY_SCOPE_AGENT) < NCONS)
            __builtin_amdgcn_s_sleep(8);
    }
    __syncthreads();
    asm volatile("s_dcache_inv" ::: "memory");     // fresh scalar-cache for wp

    int*   ballL = reinterpret_cast<int*>(smem);            // 256 ints
    float* cxl   = reinterpret_cast<float*>(smem + 1024);   // 24 floats [3][8]

    // weight base pointers in global wp (wave-uniform -> scalar loads)
    const float* w0t3 = wp;
    const float* w1t  = wp + 192;
    const float* sc0  = wp + 4288;
    const float* sh0  = wp + 4352;
    const float* sc1  = wp + 4416;
    const float* sh1  = wp + 4480;
    const float* sc2  = wp + 4544;
    const float* sh2  = wp + 4672;

    const float r2   = (float)(0.2 * 0.2);
    const int   lane = tid & 63;
    const int   wv   = tid >> 6;

    for (;;) {
        if (tid == 0)
            item_s = __hip_atomic_fetch_add(&ctrl[CTRL_QHEAD], 1,
                                            __ATOMIC_RELAXED,
                                            __HIP_MEMORY_SCOPE_AGENT);
        __syncthreads();
        const int w = item_s;
        if (w >= NITEMS) break;
        const int b  = w & 15;
        const int m0 = (w >> 4) << 3;              // 8 centroids per item

        if (tid == 0) {
            while (__hip_atomic_load(&ctrl[b], __ATOMIC_ACQUIRE,
                                     __HIP_MEMORY_SCOPE_AGENT) < m0 + 7)
                __builtin_amdgcn_s_sleep(16);
        }
        __syncthreads();

        // stage the item's 8 centroids (vector loads)
        if (tid < 24) {
            int c = tid >> 3, j = tid & 7;
            cxl[tid] = newxyz[b*3*NPOINT + c*NPOINT + m0 + j];
        }
        __syncthreads();

        // ---- ball: wave wv handles local centroids 2wv, 2wv+1 (serial) ----
        const float* xb = xyz + (size_t)b * 3 * NPTS;
        for (int cc = 0; cc < 2; ++cc) {
            const int lm = wv*2 + cc;
            const float ccx = cxl[lm], ccy = cxl[8+lm], ccz = cxl[16+lm];
            int* outi = ballL + lm * NSAMPLE;
            int base = 0, first = 0;
            for (int c0 = 0; c0 < NPTS; c0 += 64) {
                const int n = c0 + lane;
                float dx = xb[n] - ccx, dy = xb[NPTS+n] - ccy, dz = xb[2*NPTS+n] - ccz;
                float d = __fadd_rn(__fadd_rn(__fmul_rn(dx,dx), __fmul_rn(dy,dy)),
                                    __fmul_rn(dz,dz));
                bool inb = (d <= r2);
                ull mask = __ballot(inb);
                if (base == 0 && mask != 0ull) first = c0 + (int)__builtin_ctzll(mask);
                int pos = base + __popcll(mask & ((1ull << lane) - 1ull));
                if (inb && pos < NSAMPLE) outi[pos] = n;
                base += __popcll(mask);
                if (base >= NSAMPLE) break;
            }
            if (lane < NSAMPLE && lane >= base) outi[lane] = first;
        }
        __syncthreads();

        // ---- mlp: one column per thread (8 centroids x 32 samples) ----
        const int lm5 = tid >> 5;                  // local centroid 0..7
        const int m   = m0 + lm5;
        const int p   = ballL[tid];
        const float n0 = xb[p]          - cxl[lm5];
        const float n1 = xb[NPTS + p]   - cxl[8 + lm5];
        const float n2 = xb[2*NPTS + p] - cxl[16 + lm5];

        float h[64];
        const float4* Up = (const float4*)(U + ((size_t)((b << 12) | p)) * 64);
        #pragma unroll
        for (int q = 0; q < 16; ++q) {
            float4 u = Up[q];
            h[4*q+0] = u.x; h[4*q+1] = u.y; h[4*q+2] = u.z; h[4*q+3] = u.w;
        }
        #pragma unroll
        for (int o = 0; o < 64; ++o) h[o] = fmaf(w0t3[o],       n0, h[o]);
        #pragma unroll
        for (int o = 0; o < 64; ++o) h[o] = fmaf(w0t3[64 + o],  n1, h[o]);
        #pragma unroll
        for (int o = 0; o < 64; ++o) h[o] = fmaf(w0t3[128 + o], n2, h[o]);
        #pragma unroll
        for (int o = 0; o < 64; ++o)
            h[o] = fmaxf(fmaf(h[o], sc0[o], sh0[o]), 0.0f);

        float gg[64];
        #pragma unroll
        for (int o = 0; o < 64; ++o) gg[o] = 0.0f;
        #pragma unroll
        for (int k = 0; k < 64; ++k) {
            const float x = h[k];
            #pragma unroll
            for (int o = 0; o < 64; ++o) gg[o] = fmaf(w1t[k*64 + o], x, gg[o]);
        }
        #pragma unroll
        for (int o = 0; o < 64; ++o)
            gg[o] = fmaxf(fmaf(gg[o], sc1[o], sh1[o]), 0.0f);

        float* outb = out1 + (size_t)b * 128 * NPOINT + m;
        #pragma unroll 2
        for (int o = 0; o < 128; ++o) {
            float acc = 0.0f;
            const float* wr = w2 + o * 64;         // host input: scalar loads
            #pragma unroll
            for (int k = 0; k < 64; ++k) acc = fmaf(wr[k], gg[k], acc);
            acc = fmaxf(fmaf(acc, sc2[o], sh2[o]), 0.0f);
            acc = dpp_maxf<ROW_SHR1>(acc);
            acc = dpp_maxf<ROW_SHR2>(acc);
            acc = dpp_maxf<ROW_SHR4>(acc);
            acc = dpp_maxf<ROW_SHR8>(acc);
            acc = dpp_maxf<ROW_BC15>(acc);   // lane31 = max(0..31), lane63 = max(32..63)
            if ((tid & 31) == 31) outb[o * NPOINT] = acc;
        }
    }
}

// ---------------- launch ------------------------------------------------------
extern "C" void kernel_launch(void* const* d_in, const int* in_sizes, int n_in,
                              void* d_out, int out_size, void* d_ws, size_t ws_size,
                              hipStream_t stream)
{
    const float* xyz    = (const float*)d_in[0];
    const float* points = (const float*)d_in[1];
    const float* w0  = (const float*)d_in[2];
    const float* b0  = (const float*)d_in[3];
    const float* g0  = (const float*)d_in[4];
    const float* be0 = (const float*)d_in[5];
    const float* m0  = (const float*)d_in[6];
    const float* v0  = (const float*)d_in[7];
    const float* w1  = (const float*)d_in[8];
    const float* b1  = (const float*)d_in[9];
    const float* g1  = (const float*)d_in[10];
    const float* be1 = (const float*)d_in[11];
    const float* m1  = (const float*)d_in[12];
    const float* v1  = (const float*)d_in[13];
    const float* w2  = (const float*)d_in[14];
    const float* b2  = (const float*)d_in[15];
    const float* g2  = (const float*)d_in[16];
    const float* be2 = (const float*)d_in[17];
    const float* m2  = (const float*)d_in[18];
    const float* v2  = (const float*)d_in[19];

    float* out0 = (float*)d_out;                       // (16,3,1024)
    float* out1 = out0 + NBATCH * 3 * NPOINT;          // (16,128,1024)

    // workspace: ctrl (256 B) | U (16.78 MB) | wp (19.2 KB)
    int*   ctrl = (int*)d_ws;
    float* U    = (float*)((char*)d_ws + 256);
    float* wp   = (float*)((char*)d_ws + 256 + (size_t)NBATCH*NPTS*64*sizeof(float));

    hipMemsetAsync(d_ws, 0, 256, stream);              // zero progress/done/queue
    // 16 producers + 240 consumers, 1 block/CU, all co-resident (r7-verified).
    hipLaunchKernelGGL(fused_kernel, dim3(256), dim3(256), 0, stream,
                       xyz, points, w0,b0,g0,be0,m0,v0, w1,b1,g1,be1,m1,v1,
                       w2,b2,g2,be2,m2,v2, out0, out1, U, wp, ctrl);
}

// Round 16
// 1040.569 us; speedup vs baseline: 1.3294x; 1.3294x over previous
//
#include <hip/hip_runtime.h>
#include <hip/hip_bf16.h>

#define NPTS    4096
#define NBATCH  16
#define NPOINT  1024
#define NSAMPLE 32

typedef float v2f __attribute__((ext_vector_type(2)));
typedef unsigned long long ull;

// ---------------- DPP helpers (wave reductions without LDS round-trips) ---
#define ROW_SHR1  0x111
#define ROW_SHR2  0x112
#define ROW_SHR4  0x114
#define ROW_SHR8  0x118
#define ROW_BC15  0x142
#define ROW_BC31  0x143

template<int CTRL>
__device__ __forceinline__ unsigned dpp_mov(unsigned v) {
    // bound_ctrl=true: invalid source lanes produce 0 (safe identity: vals >= 0)
    return (unsigned)__builtin_amdgcn_update_dpp(0, (int)v, CTRL, 0xF, 0xF, true);
}
template<int CTRL>
__device__ __forceinline__ float dpp_maxf(float v) {
    unsigned t = dpp_mov<CTRL>(__float_as_uint(v));
    return fmaxf(v, __uint_as_float(t));
}

// ---------------- control block in workspace ---------------------------------
// ctrl[0..15]  : per-batch FPS progress (last completed iteration, rel/acq)
// ctrl[16]     : U+setup completion counter (240 consumer blocks)
// ctrl[17]     : work-item queue head
#define CTRL_DONE  16
#define CTRL_QHEAD 17
#define NCONS      240
#define NITEMS     2048          // 16384 centroids / 8 per item

// ---------------- U precompute ----------------------------------------------
// U[b*4096+p][o] = sum_{c<64} w0[o][3+c] * points[b][c][p]
__device__ void u_role(int g, const float* __restrict__ points,
                       const float* __restrict__ w0, float* __restrict__ U)
{
    const int b = g >> 12, p = g & (NPTS - 1);
    const float* pb = points + (size_t)b * 64 * NPTS + p;
    float in[64];
    #pragma unroll
    for (int c = 0; c < 64; ++c) in[c] = pb[c * NPTS];

    float* ug = U + (size_t)g * 64;
    for (int o4 = 0; o4 < 64; o4 += 4) {
        const float* r0 = w0 + (o4+0)*67 + 3;
        const float* r1 = w0 + (o4+1)*67 + 3;
        const float* r2 = w0 + (o4+2)*67 + 3;
        const float* r3 = w0 + (o4+3)*67 + 3;
        float a0 = 0.f, a1 = 0.f, a2 = 0.f, a3 = 0.f;
        #pragma unroll
        for (int c = 0; c < 64; ++c) {
            const float x = in[c];
            a0 = fmaf(r0[c], x, a0);
            a1 = fmaf(r1[c], x, a1);
            a2 = fmaf(r2[c], x, a2);
            a3 = fmaf(r3[c], x, a3);
        }
        *(float4*)(ug + o4) = make_float4(a0, a1, a2, a3);
    }
}

// ---------------- setup: transpose + BN fold ---------------------------------
__device__ void setup_role(
    const float* __restrict__ w0, const float* __restrict__ b0,
    const float* __restrict__ g0, const float* __restrict__ be0,
    const float* __restrict__ m0, const float* __restrict__ v0,
    const float* __restrict__ w1, const float* __restrict__ b1,
    const float* __restrict__ g1, const float* __restrict__ be1,
    const float* __restrict__ m1, const float* __restrict__ v1,
    const float* __restrict__ b2, const float* __restrict__ g2,
    const float* __restrict__ be2, const float* __restrict__ m2,
    const float* __restrict__ v2, float* __restrict__ wp)
{
    const int t = threadIdx.x;
    for (int i = t; i < 3*64; i += 256) {
        int k = i >> 6, o = i & 63;
        wp[i] = w0[o*67 + k];                      // w0t3 [3][64]
    }
    for (int i = t; i < 64*64; i += 256) {
        int o = i >> 6, k = i & 63;
        wp[192 + k*64 + o] = w1[i];                // w1t [64][64]
    }
    if (t < 64) {
        float s0 = g0[t] / sqrtf(v0[t] + 1e-5f);
        wp[4288 + t] = s0;
        wp[4352 + t] = (b0[t] - m0[t]) * s0 + be0[t];
        float s1 = g1[t] / sqrtf(v1[t] + 1e-5f);
        wp[4416 + t] = s1;
        wp[4480 + t] = (b1[t] - m1[t]) * s1 + be1[t];
    }
    if (t < 128) {
        float s2 = g2[t] / sqrtf(v2[t] + 1e-5f);
        wp[4544 + t] = s2;
        wp[4672 + t] = (b2[t] - m2[t]) * s2 + be2[t];
    }
}

// ---------------- fused persistent kernel ------------------------------------
// r7-verified structure (256 blocks, 1/CU, consumers identical to r7).
// ONE change vs r7: the FPS producer no longer issues global stores every
// iteration. Centroids accumulate in LDS (cbuf); tid0 flushes 16 at a time
// (12 float4 stores) right before the existing RELEASE atomic.
// LAYOUT (r15 bug fixed): P 0..65536 | slotk 65536..65600 | slotc
// 65600..65728 (float4[2][4] = 128 B!) | cbuf 65728..65920. Disjoint.
__global__ __launch_bounds__(256) void fused_kernel(
    const float* __restrict__ xyz, const float* __restrict__ points,
    const float* __restrict__ w0, const float* __restrict__ b0,
    const float* __restrict__ g0, const float* __restrict__ be0,
    const float* __restrict__ m0w, const float* __restrict__ v0,
    const float* __restrict__ w1, const float* __restrict__ b1,
    const float* __restrict__ g1, const float* __restrict__ be1,
    const float* __restrict__ m1w, const float* __restrict__ v1,
    const float* __restrict__ w2, const float* __restrict__ b2,
    const float* __restrict__ g2, const float* __restrict__ be2,
    const float* __restrict__ m2w, const float* __restrict__ v2,
    float* __restrict__ newxyz, float* __restrict__ out1,
    float* __restrict__ U, float* __restrict__ wp, int* __restrict__ ctrl)
{
    #pragma clang fp contract(off)
    __shared__ __align__(16) char smem[65920];
    __shared__ int item_s;

    if (blockIdx.x < 16) {
        // ================= FPS producer =====================================
        __builtin_amdgcn_s_setprio(2);             // win issue arbitration on CU
        float4* P     = reinterpret_cast<float4*>(smem);              // [4096]
        ull*    slotk = reinterpret_cast<ull*>(smem + 65536);         // [2][4]  64 B
        float4* slotc = reinterpret_cast<float4*>(smem + 65600);      // [2][4] 128 B
        float*  cbuf  = reinterpret_cast<float*>(smem + 65728);       // [3][16] 192 B

        const int b    = blockIdx.x;
        const int tid  = threadIdx.x;
        const int lane = tid & 63;
        const int w    = tid >> 6;
        const float* xb = xyz + (size_t)b * 3 * NPTS;

        v2f px2[8], py2[8], pz2[8], dist2[8];
        #pragma unroll
        for (int q = 0; q < 4; ++q) {
            const int n4 = tid * 16 + q * 4;
            float4 xs = *(const float4*)(xb + n4);
            float4 ys = *(const float4*)(xb + NPTS + n4);
            float4 zs = *(const float4*)(xb + 2*NPTS + n4);
            px2[2*q+0] = (v2f){xs.x, xs.y}; px2[2*q+1] = (v2f){xs.z, xs.w};
            py2[2*q+0] = (v2f){ys.x, ys.y}; py2[2*q+1] = (v2f){ys.z, ys.w};
            pz2[2*q+0] = (v2f){zs.x, zs.y}; pz2[2*q+1] = (v2f){zs.z, zs.w};
            P[n4+0] = make_float4(xs.x, ys.x, zs.x, 0.f);
            P[n4+1] = make_float4(xs.y, ys.y, zs.y, 0.f);
            P[n4+2] = make_float4(xs.z, ys.z, zs.z, 0.f);
            P[n4+3] = make_float4(xs.w, ys.w, zs.w, 0.f);
        }
        #pragma unroll
        for (int j = 0; j < 8; ++j) dist2[j] = (v2f){1e10f, 1e10f};
        __syncthreads();

        float4 c0 = P[0];
        float cx = c0.x, cy = c0.y, cz = c0.z;
        if (tid == 0) {
            cbuf[0]  = cx;                         // slot 0 of current group
            cbuf[16] = cy;
            cbuf[32] = cz;
        }

        for (int i = 1; i < NPOINT; ++i) {
            const int s = i & 1;
            const v2f cx2 = (v2f){cx, cx};
            const v2f cy2 = (v2f){cy, cy};
            const v2f cz2 = (v2f){cz, cz};
            float bv = -1.0f; int bj = 0;
            #pragma unroll
            for (int j2 = 0; j2 < 8; ++j2) {
                v2f dx = px2[j2] - cx2;
                v2f dy = py2[j2] - cy2;
                v2f dz = pz2[j2] - cz2;
                v2f xx = dx*dx, yy = dy*dy, zz = dz*dz;
                v2f dd = (xx + yy) + zz;       // same assoc as np: (x2+y2)+z2
                v2f nd;
                nd.x = fminf(dist2[j2].x, dd.x);
                nd.y = fminf(dist2[j2].y, dd.y);
                dist2[j2] = nd;
                if (nd.x > bv) { bv = nd.x; bj = 2*j2; }     // strict >: first max
                if (nd.y > bv) { bv = nd.y; bj = 2*j2+1; }
            }
            const int myidx = (tid << 4) | bj;

            float wv = bv;
            wv = dpp_maxf<ROW_SHR1>(wv);
            wv = dpp_maxf<ROW_SHR2>(wv);
            wv = dpp_maxf<ROW_SHR4>(wv);
            wv = dpp_maxf<ROW_SHR8>(wv);
            wv = dpp_maxf<ROW_BC15>(wv);
            wv = dpp_maxf<ROW_BC31>(wv);                 // lane 63 = wave max
            float wmax = __uint_as_float(
                (unsigned)__builtin_amdgcn_readlane((int)__float_as_uint(wv), 63));
            ull mask = __ballot(bv == wmax);
            int L = (int)__builtin_ctzll(mask);          // first lane = min idx
            int widx = __builtin_amdgcn_readlane(myidx, L);

            float4 cand = P[widx];                       // uniform-addr broadcast
            if (lane == 0) {
                slotk[s*4 + w] = ((ull)__float_as_uint(wmax) << 32) |
                                 (ull)(unsigned)(~widx);
                slotc[s*4 + w] = cand;
            }
            __syncthreads();

            ull k0 = slotk[s*4+0], k1 = slotk[s*4+1];
            ull k2 = slotk[s*4+2], k3 = slotk[s*4+3];
            float4 s0 = slotc[s*4+0], s1 = slotc[s*4+1];
            float4 s2 = slotc[s*4+2], s3 = slotc[s*4+3];
            bool b01 = k1 > k0;
            ull ka = b01 ? k1 : k0;
            float ax = b01 ? s1.x : s0.x, ay = b01 ? s1.y : s0.y, az = b01 ? s1.z : s0.z;
            bool b23 = k3 > k2;
            ull kb = b23 ? k3 : k2;
            float bx = b23 ? s3.x : s2.x, by = b23 ? s3.y : s2.y, bz = b23 ? s3.z : s2.z;
            bool ab = kb > ka;
            cx = ab ? bx : ax; cy = ab ? by : ay; cz = ab ? bz : az;

            if (tid == 0) {
                const int sl = i & 15;
                cbuf[sl]      = cx;                // LDS only - cheap drain
                cbuf[16 + sl] = cy;
                cbuf[32 + sl] = cz;
                if (sl == 15) {
                    // flush 16 centroids: 12 coalesced float4 stores, then
                    // RELEASE atomic (same-thread order = r7-proven pattern)
                    const int i0 = i - 15;
                    #pragma unroll
                    for (int c = 0; c < 3; ++c) {
                        float4* dst = (float4*)(newxyz + b*3*NPOINT + c*NPOINT + i0);
                        const float4* src = (const float4*)(cbuf + 16*c);
                        dst[0] = src[0]; dst[1] = src[1];
                        dst[2] = src[2]; dst[3] = src[3];
                    }
                    __hip_atomic_store(&ctrl[b], i, __ATOMIC_RELEASE,
                                       __HIP_MEMORY_SCOPE_AGENT);
                }
            }
        }
        return;
    }

    // ================= consumer: U/setup, then streamed ball+mlp =============
    // (byte-identical to the r7 kernel that ran and passed twice)
    __builtin_amdgcn_s_setprio(0);
    const int cb  = blockIdx.x - 16;               // 0..239
    const int tid = threadIdx.x;

    // phase 0: U slice (+ weight prep on first consumer)
    for (int g = cb * 256 + tid; g < NBATCH * NPTS; g += NCONS * 256)
        u_role(g, points, w0, U);
    if (cb == 0)
        setup_role(w0,b0,g0,be0,m0w,v0, w1,b1,g1,be1,m1w,v1,
                   b2,g2,be2,m2w,v2, wp);
    __syncthreads();
    if (tid == 0) {
        __hip_atomic_fetch_add(&ctrl[CTRL_DONE], 1, __ATOMIC_ACQ_REL,
                               __HIP_MEMORY_SCOPE_AGENT);
        while (__hip_atomic_load(&ctrl[CTRL_DONE], __ATOMIC_ACQUIRE,
                                 __HIP_MEMORY_SCOPE_AGENT) < NCONS)
            __builtin_amdgcn_s_sleep(8);
    }
    __syncthreads();
    asm volatile("s_dcache_inv" ::: "memory");     // kill stale scalar-cache lines

    float* wpl   = reinterpret_cast<float*>(smem);          // 4800 floats
    int*   ballL = reinterpret_cast<int*>(smem + 19200);    // 256 ints
    float* cxl   = reinterpret_cast<float*>(smem + 20224);  // 24 floats [3][8]

    for (int i2 = tid; i2 < 4800; i2 += 256) wpl[i2] = wp[i2];  // vector loads
    __syncthreads();

    const float r2   = (float)(0.2 * 0.2);
    const int   lane = tid & 63;
    const int   wv   = tid >> 6;

    for (;;) {
        if (tid == 0)
            item_s = __hip_atomic_fetch_add(&ctrl[CTRL_QHEAD], 1,
                                            __ATOMIC_RELAXED,
                                            __HIP_MEMORY_SCOPE_AGENT);
        __syncthreads();
        const int w = item_s;
        if (w >= NITEMS) break;
        const int b  = w & 15;
        const int m0 = (w >> 4) << 3;              // 8 centroids per item

        if (tid == 0) {
            while (__hip_atomic_load(&ctrl[b], __ATOMIC_ACQUIRE,
                                     __HIP_MEMORY_SCOPE_AGENT) < m0 + 7)
                __builtin_amdgcn_s_sleep(16);
        }
        __syncthreads();

        // stage the item's 8 centroids (vector loads)
        if (tid < 24) {
            int c = tid >> 3, j = tid & 7;
            cxl[tid] = newxyz[b*3*NPOINT + c*NPOINT + m0 + j];
        }
        __syncthreads();

        // ---- ball: wave wv handles local centroids 2wv, 2wv+1 (serial) ----
        const float* xb = xyz + (size_t)b * 3 * NPTS;
        for (int cc = 0; cc < 2; ++cc) {
            const int lm = wv*2 + cc;
            const float ccx = cxl[lm], ccy = cxl[8+lm], ccz = cxl[16+lm];
            int* outi = ballL + lm * NSAMPLE;
            int base = 0, first = 0;
            for (int c0 = 0; c0 < NPTS; c0 += 64) {
                const int n = c0 + lane;
                float dx = xb[n] - ccx, dy = xb[NPTS+n] - ccy, dz = xb[2*NPTS+n] - ccz;
                float d = __fadd_rn(__fadd_rn(__fmul_rn(dx,dx), __fmul_rn(dy,dy)),
                                    __fmul_rn(dz,dz));
                bool inb = (d <= r2);
                ull mask = __ballot(inb);
                if (base == 0 && mask != 0ull) first = c0 + (int)__builtin_ctzll(mask);
                int pos = base + __popcll(mask & ((1ull << lane) - 1ull));
                if (inb && pos < NSAMPLE) outi[pos] = n;
                base += __popcll(mask);
                if (base >= NSAMPLE) break;
            }
            if (lane < NSAMPLE && lane >= base) outi[lane] = first;
        }
        __syncthreads();

        // ---- mlp: one column per thread (8 centroids x 32 samples) ----
        const int lm5 = tid >> 5;                  // local centroid 0..7
        const int m   = m0 + lm5;
        const int p   = ballL[tid];
        const float n0 = xb[p]          - cxl[lm5];
        const float n1 = xb[NPTS + p]   - cxl[8 + lm5];
        const float n2 = xb[2*NPTS + p] - cxl[16 + lm5];

        const float* w0t3 = wpl;
        const float* w1t  = wpl + 192;
        const float* sc0  = wpl + 4288;
        const float* sh0  = wpl + 4352;
        const float* sc1  = wpl + 4416;
        const float* sh1  = wpl + 4480;
        const float* sc2  = wpl + 4544;
        const float* sh2  = wpl + 4672;

        float h[64];
        const float4* Up = (const float4*)(U + ((size_t)((b << 12) | p)) * 64);
        #pragma unroll
        for (int q = 0; q < 16; ++q) {
            float4 u = Up[q];
            h[4*q+0] = u.x; h[4*q+1] = u.y; h[4*q+2] = u.z; h[4*q+3] = u.w;
        }
        #pragma unroll
        for (int o = 0; o < 64; ++o) h[o] = fmaf(w0t3[o],       n0, h[o]);
        #pragma unroll
        for (int o = 0; o < 64; ++o) h[o] = fmaf(w0t3[64 + o],  n1, h[o]);
        #pragma unroll
        for (int o = 0; o < 64; ++o) h[o] = fmaf(w0t3[128 + o], n2, h[o]);
        #pragma unroll
        for (int o = 0; o < 64; ++o)
            h[o] = fmaxf(fmaf(h[o], sc0[o], sh0[o]), 0.0f);

        float gg[64];
        #pragma unroll
        for (int o = 0; o < 64; ++o) gg[o] = 0.0f;
        #pragma unroll
        for (int k = 0; k < 64; ++k) {
            const float x = h[k];
            #pragma unroll
            for (int o = 0; o < 64; ++o) gg[o] = fmaf(w1t[k*64 + o], x, gg[o]);
        }
        #pragma unroll
        for (int o = 0; o < 64; ++o)
            gg[o] = fmaxf(fmaf(gg[o], sc1[o], sh1[o]), 0.0f);

        float* outb = out1 + (size_t)b * 128 * NPOINT + m;
        #pragma unroll 2
        for (int o = 0; o < 128; ++o) {
            float acc = 0.0f;
            const float* wr = w2 + o * 64;         // host input: scalar loads safe
            #pragma unroll
            for (int k = 0; k < 64; ++k) acc = fmaf(wr[k], gg[k], acc);
            acc = fmaxf(fmaf(acc, sc2[o], sh2[o]), 0.0f);
            acc = dpp_maxf<ROW_SHR1>(acc);
            acc = dpp_maxf<ROW_SHR2>(acc);
            acc = dpp_maxf<ROW_SHR4>(acc);
            acc = dpp_maxf<ROW_SHR8>(acc);
            acc = dpp_maxf<ROW_BC15>(acc);   // lane31 = max(0..31), lane63 = max(32..63)
            if ((tid & 31) == 31) outb[o * NPOINT] = acc;
        }
    }
}

// ---------------- launch ------------------------------------------------------
extern "C" void kernel_launch(void* const* d_in, const int* in_sizes, int n_in,
                              void* d_out, int out_size, void* d_ws, size_t ws_size,
                              hipStream_t stream)
{
    const float* xyz    = (const float*)d_in[0];
    const float* points = (const float*)d_in[1];
    const float* w0  = (const float*)d_in[2];
    const float* b0  = (const float*)d_in[3];
    const float* g0  = (const float*)d_in[4];
    const float* be0 = (const float*)d_in[5];
    const float* m0  = (const float*)d_in[6];
    const float* v0  = (const float*)d_in[7];
    const float* w1  = (const float*)d_in[8];
    const float* b1  = (const float*)d_in[9];
    const float* g1  = (const float*)d_in[10];
    const float* be1 = (const float*)d_in[11];
    const float* m1  = (const float*)d_in[12];
    const float* v1  = (const float*)d_in[13];
    const float* w2  = (const float*)d_in[14];
    const float* b2  = (const float*)d_in[15];
    const float* g2  = (const float*)d_in[16];
    const float* be2 = (const float*)d_in[17];
    const float* m2  = (const float*)d_in[18];
    const float* v2  = (const float*)d_in[19];

    float* out0 = (float*)d_out;                       // (16,3,1024)
    float* out1 = out0 + NBATCH * 3 * NPOINT;          // (16,128,1024)

    // workspace: ctrl (256 B) | U (16.78 MB) | wp (19.2 KB)
    int*   ctrl = (int*)d_ws;
    float* U    = (float*)((char*)d_ws + 256);
    float* wp   = (float*)((char*)d_ws + 256 + (size_t)NBATCH*NPTS*64*sizeof(float));

    hipMemsetAsync(d_ws, 0, 256, stream);              // zero progress/done/queue
    // 16 producers + 240 consumers, 1 block/CU, all co-resident (r7-verified).
    hipLaunchKernelGGL(fused_kernel, dim3(256), dim3(256), 0, stream,
                       xyz, points, w0,b0,g0,be0,m0,v0, w1,b1,g1,be1,m1,v1,
                       w2,b2,g2,be2,m2,v2, out0, out1, U, wp, ctrl);
}